// Round 7
// baseline (102562.146 us; speedup 1.0000x reference)
//
#include <hip/hip_runtime.h>
#include <stdint.h>

typedef unsigned short u16;

#define BB    16
#define TENC  256
#define TDEC  200
#define NMELS 80
#define EDIM  512
#define PREN  256
#define ARN   1024
#define ATTN  128
#define NFILT 32
#define KSIZE 31
#define NBLK  256

// ---- workspace layout (floats). Proven budget: ws_size >= 7.44 MB (R3); total here 6.82 MB.
#define OFF_ARRIVE 0          // 256 barrier slots x 16 ints (64B apart)
#define OFF_GEN    4096
#define OFF_AW     4160       // [b][tt] 4096
#define OFF_AWC    8256       // 4096
#define OFF_AC     12352      // [b][u] 16384
#define OFF_DC     28736      // 16384
#define OFF_AHT    45120      // [u*16+b] 16384
#define OFF_DHT    61504      // 16384
#define OFF_DH     77888      // [b][u] 16384
#define OFF_CTX    94272      // [b][e] 8192
#define OFF_CTXT   102464     // [e*16+b] 8192
#define OFF_XPRE   110656     // [j*16+b] 4096 (f32 slice of pre for current t)
#define STATE_F    114752
#define OFF_PRETU  114752     // u16[819200] : pre, [t*4096 + j*16 + b]
#define OFF_PMU    524352     // u16[524288] : pm transposed [b][j][tt]
#define OFF_Z      786496     // f32[917504] : split-K partials (14 chunks max)

__host__ __device__ inline void tf2x32(uint32_t k0, uint32_t k1, uint32_t x0, uint32_t x1,
                                       uint32_t &y0, uint32_t &y1) {
  uint32_t ks2 = k0 ^ k1 ^ 0x1BD11BDAu;
  x0 += k0; x1 += k1;
  const int R0[4] = {13, 15, 26, 6};
  const int R1[4] = {17, 29, 16, 24};
#pragma unroll
  for (int g = 0; g < 5; ++g) {
    const int *R = (g & 1) ? R1 : R0;
#pragma unroll
    for (int i = 0; i < 4; ++i) {
      x0 += x1;
      x1 = (x1 << R[i]) | (x1 >> (32 - R[i]));
      x1 ^= x0;
    }
    switch (g) {
      case 0: x0 += k1;  x1 += ks2 + 1u; break;
      case 1: x0 += ks2; x1 += k0 + 2u;  break;
      case 2: x0 += k0;  x1 += k1 + 3u;  break;
      case 3: x0 += k1;  x1 += ks2 + 4u; break;
      case 4: x0 += ks2; x1 += k0 + 5u;  break;
    }
  }
  y0 = x0; y1 = x1;
}

__device__ inline bool keep_mask(uint32_t k0, uint32_t k1, uint32_t idx) {
  uint32_t y0, y1;
  tf2x32(k0, k1, 0u, idx, y0, y1);
  return (((y0 ^ y1) >> 31) == 0u);
}

__device__ inline float bf2f(u16 v) {
  union { uint32_t u; float f; } x;
  x.u = ((uint32_t)v) << 16;
  return x.f;
}
__device__ inline u16 f2bf(float f) {
  union { float f; uint32_t u; } x;
  x.f = f;
  uint32_t r = ((x.u >> 16) & 1u) + 0x7FFFu;
  return (u16)((x.u + r) >> 16);
}
__device__ inline float sigm(float x) { return 1.f / (1.f + __expf(-x)); }
__device__ inline float ftanh(float x) {
  x = fminf(fmaxf(x, -15.f), 15.f);
  float e = __expf(2.f * x);
  return (e - 1.f) / (e + 1.f);
}

// ---------------- prenet layer 1: x1(bf16) = mask1(relu(di @ W1)) * 2 ----------------
__global__ __launch_bounds__(256) void k_prenet1(const float *__restrict__ dec_in,
                                                 const float *__restrict__ W1,
                                                 u16 *__restrict__ x1,
                                                 uint32_t k0, uint32_t k1) {
  int bid = blockIdx.x;
  int t = bid >> 4, b = bid & 15;
  int tid = threadIdx.x;
  __shared__ float di[NMELS];
  if (tid < NMELS)
    di[tid] = (t == 0) ? 0.f : dec_in[((size_t)b * NMELS + tid) * TDEC + (t - 1)];
  __syncthreads();
  int j = tid;
  float acc = 0.f;
#pragma unroll 4
  for (int m = 0; m < NMELS; ++m) acc += di[m] * W1[(size_t)m * PREN + j];
  acc = fmaxf(acc, 0.f);
  uint32_t idx = ((uint32_t)(t * BB + b)) * PREN + (uint32_t)j;
  acc = keep_mask(k0, k1, idx) ? acc * 2.f : 0.f;
  x1[(t * BB + b) * PREN + j] = f2bf(acc);
}

// ---------------- prenet layer 2 -> preTu (bf16, [t][j][b]) ----------------
__global__ __launch_bounds__(256) void k_prenet2(const u16 *__restrict__ x1,
                                                 const float *__restrict__ W2,
                                                 u16 *__restrict__ preTu,
                                                 uint32_t k0, uint32_t k1) {
  int bid = blockIdx.x;
  int t = bid >> 4, b = bid & 15;
  int tid = threadIdx.x;
  __shared__ float xl[PREN];
  xl[tid] = bf2f(x1[(t * BB + b) * PREN + tid]);
  __syncthreads();
  int j = tid;
  float acc = 0.f;
#pragma unroll 4
  for (int k = 0; k < PREN; ++k) acc += xl[k] * W2[(size_t)k * PREN + j];
  acc = fmaxf(acc, 0.f);
  uint32_t idx = ((uint32_t)(t * BB + b)) * PREN + (uint32_t)j;
  acc = keep_mask(k0, k1, idx) ? acc * 2.f : 0.f;
  preTu[(size_t)t * 4096 + j * 16 + b] = f2bf(acc);
}

// ---------------- pm = memory @ Wmem, stored bf16 TRANSPOSED [b][j][tt] ----------------
__global__ __launch_bounds__(256) void k_pm(const float *__restrict__ memory,
                                            const float *__restrict__ Wmem,
                                            u16 *__restrict__ pmu) {
  int p = blockIdx.x;          // 64 blocks
  int b = p & 15, jt = p >> 4; // jt < 4 (32 j each)
  int tt = threadIdx.x;
  float acc[32];
#pragma unroll
  for (int j = 0; j < 32; ++j) acc[j] = 0.f;
  const float *mrow = memory + ((size_t)b * TENC + tt) * EDIM;
  const float *wb = Wmem + jt * 32;
  for (int e = 0; e < EDIM; ++e) {
    float mv = mrow[e];
    const float *wr = wb + (size_t)e * ATTN;   // uniform -> s_load (const data)
#pragma unroll
    for (int j = 0; j < 32; ++j) acc[j] += mv * wr[j];
  }
#pragma unroll
  for (int j = 0; j < 32; ++j)
    pmu[((size_t)(b * ATTN + jt * 32 + j)) * TENC + tt] = f2bf(acc[j]);
}

// ---------------- persistent decoder kernel ----------------
union SMem {
  struct { float xs[2048]; } z;                                   // GEMM x-chunk stage
  struct { float ah[1024], awl[288], awcl[288], lc[256 * 33],
           pq[128], el[256], red[32], mx[2]; } a;                 // attention
  struct { float wl[256], part[256]; } c;                         // ctx
  struct { float p[1024]; } o1;                                   // dLSTM act reduce
  struct { float xl[1536], part[256]; } o2;                       // projection
};

__device__ inline void gbar(int *arrive, int *gen, int g) {
  __syncthreads();
  if (threadIdx.x == 0)
    __hip_atomic_store(&arrive[blockIdx.x * 16], g, __ATOMIC_RELEASE, __HIP_MEMORY_SCOPE_AGENT);
  if (blockIdx.x == 0) {
    if (threadIdx.x < 64) {
      for (;;) {
        bool ok = true;
        for (int i = threadIdx.x; i < NBLK; i += 64)
          if (__hip_atomic_load(&arrive[i * 16], __ATOMIC_RELAXED, __HIP_MEMORY_SCOPE_AGENT) < g)
            ok = false;
        if (!__ballot(!ok)) break;
      }
      if (threadIdx.x == 0)
        __hip_atomic_store(gen, g, __ATOMIC_RELEASE, __HIP_MEMORY_SCOPE_AGENT);
    }
  } else if (threadIdx.x == 0) {
    while (__hip_atomic_load(gen, __ATOMIC_RELAXED, __HIP_MEMORY_SCOPE_AGENT) < g) {}
  }
  __threadfence();
  __syncthreads();
}

__global__ __launch_bounds__(256, 1) void k_persist(
    float *__restrict__ ws,
    const float *__restrict__ memory, const int *__restrict__ mlen,
    const float *__restrict__ aWih, const float *__restrict__ aWhh, const float *__restrict__ ab,
    const float *__restrict__ Wq, const float *__restrict__ vw,
    const float *__restrict__ convW, const float *__restrict__ ldW,
    const float *__restrict__ dWih, const float *__restrict__ dWhh, const float *__restrict__ db,
    const float *__restrict__ projW, const float *__restrict__ projB,
    const float *__restrict__ gateW, const float *__restrict__ gateB,
    float *__restrict__ mel_out, float *__restrict__ gate_out, float *__restrict__ align_out) {
  __shared__ SMem sm;
  int p = blockIdx.x, tid = threadIdx.x;

  int *arrive = (int *)(ws + OFF_ARRIVE);
  int *gen = (int *)(ws + OFF_GEN);
  float *aw = ws + OFF_AW, *awc = ws + OFF_AWC;
  float *ac = ws + OFF_AC, *dc = ws + OFF_DC;
  float *ahT = ws + OFF_AHT, *dhT = ws + OFF_DHT, *dh = ws + OFF_DH;
  float *ctx = ws + OFF_CTX, *ctxT = ws + OFF_CTXT, *xpre = ws + OFF_XPRE;
  const u16 *preTu = (const u16 *)(ws + OFF_PRETU);
  const u16 *pmu = (const u16 *)(ws + OFF_PMU);
  float *z = ws + OFF_Z;

  int g = 0;

  // P0: stage pre slice for t=0
  if (p >= 224) {
    int idx = (p - 224) * 256 + tid;
    if (idx < 4096) xpre[idx] = bf2f(preTu[idx]);
  }
  gbar(arrive, gen, ++g);

  for (int t = 0; t < TDEC; ++t) {
    // ---- Z1: aLSTM pre-act partials. 224 blocks: ct(16 x 256cols) x kc(14 x 128K) ----
    if (p < 224) {
      int ct = p & 15, kc = p >> 4;
      int col = ct * 256 + tid;
      int kbase = kc * 128;
      const float *xsrc = (kbase < 256) ? (xpre + kbase * 16)
                        : (kbase < 768) ? (ctxT + (kbase - 256) * 16)
                                        : (ahT + (kbase - 768) * 16);
      const float *W = (kbase < 768) ? aWih : aWhh;
      int wrow = (kbase < 768) ? kbase : kbase - 768;
      ((float4 *)sm.z.xs)[tid] = ((const float4 *)xsrc)[tid];
      ((float4 *)sm.z.xs)[256 + tid] = ((const float4 *)xsrc)[256 + tid];
      __syncthreads();
      const float *wp = W + (size_t)wrow * 4096 + col;
      float4 s0 = {0,0,0,0}, s1 = {0,0,0,0}, s2 = {0,0,0,0}, s3 = {0,0,0,0};
#pragma unroll 2
      for (int kk = 0; kk < 128; ++kk) {
        float w = wp[(size_t)kk * 4096];
        const float4 *xr = (const float4 *)(sm.z.xs + kk * 16);
        float4 a0 = xr[0], a1 = xr[1], a2 = xr[2], a3 = xr[3];
        s0.x += a0.x*w; s0.y += a0.y*w; s0.z += a0.z*w; s0.w += a0.w*w;
        s1.x += a1.x*w; s1.y += a1.y*w; s1.z += a1.z*w; s1.w += a1.w*w;
        s2.x += a2.x*w; s2.y += a2.y*w; s2.z += a2.z*w; s2.w += a2.w*w;
        s3.x += a3.x*w; s3.y += a3.y*w; s3.z += a3.z*w; s3.w += a3.w*w;
      }
      float *zo = z + ((size_t)kc * 16) * 4096 + col;
      zo[0] = s0.x; zo[4096] = s0.y; zo[2*4096] = s0.z; zo[3*4096] = s0.w;
      zo[4*4096] = s1.x; zo[5*4096] = s1.y; zo[6*4096] = s1.z; zo[7*4096] = s1.w;
      zo[8*4096] = s2.x; zo[9*4096] = s2.y; zo[10*4096] = s2.z; zo[11*4096] = s2.w;
      zo[12*4096] = s3.x; zo[13*4096] = s3.y; zo[14*4096] = s3.z; zo[15*4096] = s3.w;
    }
    gbar(arrive, gen, ++g);

    // ---- A: aLSTM act + attention (16 blocks, one per b) ----
    if (p < 16) {
      int b = p;
      for (int r = 0; r < 4; ++r) {
        int u = r * 256 + tid;
        float zi = 0.f, zf = 0.f, zg = 0.f, zo = 0.f;
        for (int kc = 0; kc < 14; ++kc) {
          const float *zb = z + ((size_t)(kc * 16 + b)) * 4096;
          zi += zb[u]; zf += zb[u + 1024]; zg += zb[u + 2048]; zo += zb[u + 3072];
        }
        zi += ab[u]; zf += ab[u + 1024]; zg += ab[u + 2048]; zo += ab[u + 3072];
        float cn = sigm(zf) * ac[b * 1024 + u] + sigm(zi) * ftanh(zg);
        float hn = sigm(zo) * ftanh(cn);
        ac[b * 1024 + u] = cn;
        ahT[u * 16 + b] = hn;
        sm.a.ah[u] = hn;
      }
      sm.a.awl[16 + tid] = aw[b * 256 + tid];
      sm.a.awcl[16 + tid] = awc[b * 256 + tid];
      if (tid < 16) {
        sm.a.awl[tid] = 0.f; sm.a.awl[272 + tid] = 0.f;
        sm.a.awcl[tid] = 0.f; sm.a.awcl[272 + tid] = 0.f;
      }
      __syncthreads();
      // conv (thread = tt)
      {
        float facc[32];
#pragma unroll
        for (int f = 0; f < 32; ++f) facc[f] = 0.f;
        for (int k = 0; k < KSIZE; ++k) {
          float a = sm.a.awl[tid + k + 1];
          float c = sm.a.awcl[tid + k + 1];
#pragma unroll
          for (int f = 0; f < 32; ++f)
            facc[f] += a * convW[f * 62 + k] + c * convW[f * 62 + 31 + k];
        }
#pragma unroll
        for (int f = 0; f < 32; ++f) sm.a.lc[tid * 33 + f] = facc[f];
      }
      // pq partials (thread = (j, half))
      {
        int j = tid & 127, h = tid >> 7;
        float a = 0.f;
        const float *wq = Wq + (size_t)h * 512 * 128 + j;
        for (int kk = 0; kk < 512; kk += 4) {
          float4 av = *(const float4 *)(sm.a.ah + h * 512 + kk);
          a += av.x * wq[(size_t)kk * 128] + av.y * wq[(size_t)(kk + 1) * 128]
             + av.z * wq[(size_t)(kk + 2) * 128] + av.w * wq[(size_t)(kk + 3) * 128];
        }
        sm.a.el[tid] = a;
      }
      __syncthreads();
      if (tid < 128) sm.a.pq[tid] = sm.a.el[tid] + sm.a.el[128 + tid];
      __syncthreads();
      // energies (thread = tt; 64 register accumulators x 2 halves)
      {
        int len = mlen[b];
        float lcreg[32];
#pragma unroll
        for (int f = 0; f < 32; ++f) lcreg[f] = sm.a.lc[tid * 33 + f];
        float esum = 0.f;
        for (int jh = 0; jh < 2; ++jh) {
          float acc[64];
#pragma unroll
          for (int j = 0; j < 64; ++j) acc[j] = 0.f;
          for (int f = 0; f < 32; ++f) {
            const float *lw = ldW + f * 128 + jh * 64;  // uniform const -> s_load
            float lv = lcreg[f];
#pragma unroll
            for (int j = 0; j < 64; ++j) acc[j] += lv * lw[j];
          }
          const u16 *pmrow = pmu + ((size_t)(b * 128 + jh * 64)) * 256 + tid;
          const float *vwh = vw + jh * 64;
#pragma unroll 4
          for (int j = 0; j < 64; ++j) {
            float s = acc[j] + sm.a.pq[jh * 64 + j] + bf2f(pmrow[(size_t)j * 256]);
            esum += ftanh(s) * vwh[j];
          }
        }
        sm.a.el[tid] = (tid < len) ? esum : -1e9f;
      }
      __syncthreads();
      if (tid < 32) {
        float m = -1e30f;
#pragma unroll
        for (int i = 0; i < 8; ++i) m = fmaxf(m, sm.a.el[tid * 8 + i]);
        sm.a.red[tid] = m;
      }
      __syncthreads();
      if (tid == 0) {
        float m = -1e30f;
        for (int i = 0; i < 32; ++i) m = fmaxf(m, sm.a.red[i]);
        sm.a.mx[0] = m;
      }
      __syncthreads();
      sm.a.el[tid] = __expf(sm.a.el[tid] - sm.a.mx[0]);
      __syncthreads();
      if (tid < 32) {
        float s = 0.f;
#pragma unroll
        for (int i = 0; i < 8; ++i) s += sm.a.el[tid * 8 + i];
        sm.a.red[tid] = s;
      }
      __syncthreads();
      if (tid == 0) {
        float s = 0.f;
        for (int i = 0; i < 32; ++i) s += sm.a.red[i];
        sm.a.mx[1] = 1.f / s;
      }
      __syncthreads();
      {
        float wv = sm.a.el[tid] * sm.a.mx[1];
        aw[b * 256 + tid] = wv;
        awc[b * 256 + tid] = sm.a.awcl[16 + tid] + wv;
        align_out[((size_t)b * TDEC + t) * TENC + tid] = wv;
      }
    }
    gbar(arrive, gen, ++g);

    // ---- C: ctx = w @ memory (128 blocks: b x 8 e-chunks of 64) ----
    if (p < 128) {
      int b = p & 15, ec = p >> 4;
      sm.c.wl[tid] = aw[b * 256 + tid];   // per-lane load (coherent)
      __syncthreads();
      int lane = tid & 63, tg = tid >> 6;
      int e = ec * 64 + lane;
      float a = 0.f;
      const float *mrow = memory + ((size_t)b * TENC + tg * 64) * EDIM + e;
#pragma unroll 4
      for (int i = 0; i < 64; i += 4) {
        float4 w4 = *(const float4 *)(sm.c.wl + tg * 64 + i);
        a += w4.x * mrow[(size_t)i * 512] + w4.y * mrow[(size_t)(i + 1) * 512]
           + w4.z * mrow[(size_t)(i + 2) * 512] + w4.w * mrow[(size_t)(i + 3) * 512];
      }
      sm.c.part[tg * 64 + lane] = a;
      __syncthreads();
      if (tid < 64) {
        int ee = ec * 64 + tid;
        float v = sm.c.part[tid] + sm.c.part[64 + tid] + sm.c.part[128 + tid] + sm.c.part[192 + tid];
        ctx[b * 512 + ee] = v;
        ctxT[ee * 16 + b] = v;
      }
    }
    gbar(arrive, gen, ++g);

    // ---- Z2: dLSTM pre-act partials. 160 blocks: ct(16) x kcp(10); 2 sub-chunks each ----
    if (p < 160) {
      int ct = p & 15, kcp = p / 16;
      int col = ct * 256 + tid;
      float4 s0 = {0,0,0,0}, s1 = {0,0,0,0}, s2 = {0,0,0,0}, s3 = {0,0,0,0};
      for (int half = 0; half < 2; ++half) {
        int kb = (kcp + half * 10) * 128;
        const float *xsrc = (kb < 1024) ? (ahT + kb * 16)
                          : (kb < 1536) ? (ctxT + (kb - 1024) * 16)
                                        : (dhT + (kb - 1536) * 16);
        const float *W = (kb < 1536) ? dWih : dWhh;
        int wrow = (kb < 1536) ? kb : kb - 1536;
        __syncthreads();
        ((float4 *)sm.z.xs)[tid] = ((const float4 *)xsrc)[tid];
        ((float4 *)sm.z.xs)[256 + tid] = ((const float4 *)xsrc)[256 + tid];
        __syncthreads();
        const float *wp = W + (size_t)wrow * 4096 + col;
#pragma unroll 2
        for (int kk = 0; kk < 128; ++kk) {
          float w = wp[(size_t)kk * 4096];
          const float4 *xr = (const float4 *)(sm.z.xs + kk * 16);
          float4 a0 = xr[0], a1 = xr[1], a2 = xr[2], a3 = xr[3];
          s0.x += a0.x*w; s0.y += a0.y*w; s0.z += a0.z*w; s0.w += a0.w*w;
          s1.x += a1.x*w; s1.y += a1.y*w; s1.z += a1.z*w; s1.w += a1.w*w;
          s2.x += a2.x*w; s2.y += a2.y*w; s2.z += a2.z*w; s2.w += a2.w*w;
          s3.x += a3.x*w; s3.y += a3.y*w; s3.z += a3.z*w; s3.w += a3.w*w;
        }
      }
      float *zo = z + ((size_t)kcp * 16) * 4096 + col;
      zo[0] = s0.x; zo[4096] = s0.y; zo[2*4096] = s0.z; zo[3*4096] = s0.w;
      zo[4*4096] = s1.x; zo[5*4096] = s1.y; zo[6*4096] = s1.z; zo[7*4096] = s1.w;
      zo[8*4096] = s2.x; zo[9*4096] = s2.y; zo[10*4096] = s2.z; zo[11*4096] = s2.w;
      zo[12*4096] = s3.x; zo[13*4096] = s3.y; zo[14*4096] = s3.z; zo[15*4096] = s3.w;
    }
    gbar(arrive, gen, ++g);

    // ---- O1: dLSTM act (256 blocks: b x 16 u-chunks of 64) ----
    {
      int b = p & 15, uc = p >> 4;
      int lane = tid & 63, kg = tid >> 6;
      int u = uc * 64 + lane;
      float zi = 0.f, zf = 0.f, zg = 0.f, zo = 0.f;
      for (int kc = kg; kc < 10; kc += 4) {
        const float *zb = z + ((size_t)(kc * 16 + b)) * 4096;
        zi += zb[u]; zf += zb[u + 1024]; zg += zb[u + 2048]; zo += zb[u + 3072];
      }
      float *pp = sm.o1.p + kg * 256 + lane * 4;
      pp[0] = zi; pp[1] = zf; pp[2] = zg; pp[3] = zo;
      __syncthreads();
      if (kg == 0) {
#pragma unroll
        for (int k2 = 1; k2 < 4; ++k2) {
          const float *q = sm.o1.p + k2 * 256 + lane * 4;
          zi += q[0]; zf += q[1]; zg += q[2]; zo += q[3];
        }
        zi += db[u]; zf += db[u + 1024]; zg += db[u + 2048]; zo += db[u + 3072];
        float cn = sigm(zf) * dc[b * 1024 + u] + sigm(zi) * ftanh(zg);
        float hn = sigm(zo) * ftanh(cn);
        dc[b * 1024 + u] = cn;
        dh[b * 1024 + u] = hn;
        dhT[u * 16 + b] = hn;
      }
    }
    gbar(arrive, gen, ++g);

    // ---- O2: projection (224 blocks: b x 14 col-groups of 6) + stage next pre slice ----
    if (p < 224) {
      int b = p & 15, cg = p >> 4;
      for (int i = tid; i < 1536; i += 256)
        sm.o2.xl[i] = (i < 1024) ? dh[b * 1024 + i] : ctx[b * 512 + (i - 1024)];
      __syncthreads();
      int c = tid & 7, kc = tid >> 3;
      int col = cg * 6 + c;
      float a = 0.f;
      if (c < 6 && col <= 80) {
        for (int kk = 0; kk < 48; ++kk) {
          int k = kc * 48 + kk;
          float wv = (col < 80) ? projW[(size_t)k * 80 + col] : gateW[k];
          a += sm.o2.xl[k] * wv;
        }
      }
      sm.o2.part[kc * 8 + c] = a;
      __syncthreads();
      if (tid < 8) {
        int col2 = cg * 6 + tid;
        if (tid < 6 && col2 <= 80) {
          float s = 0.f;
          for (int k2 = 0; k2 < 32; ++k2) s += sm.o2.part[k2 * 8 + tid];
          if (col2 < 80) {
            s += projB[col2];
            mel_out[((size_t)b * 80 + col2) * TDEC + t] = s;
          } else {
            s += gateB[0];
            gate_out[(size_t)b * TDEC + t] = s;
          }
        }
      }
    } else if (t + 1 < TDEC) {
      int idx = (p - 224) * 256 + tid;
      if (idx < 4096) xpre[idx] = bf2f(preTu[(size_t)(t + 1) * 4096 + idx]);
    }
    gbar(arrive, gen, ++g);
  }
}

extern "C" void kernel_launch(void *const *d_in, const int *in_sizes, int n_in,
                              void *d_out, int out_size, void *d_ws, size_t ws_size,
                              hipStream_t stream) {
  (void)in_sizes; (void)n_in; (void)out_size; (void)ws_size;
  const float *memory = (const float *)d_in[0];
  const float *dec_in = (const float *)d_in[1];
  const int   *mlen   = (const int *)d_in[2];
  const float *pw1    = (const float *)d_in[3];
  const float *pw2    = (const float *)d_in[4];
  const float *aWih   = (const float *)d_in[5];
  const float *aWhh   = (const float *)d_in[6];
  const float *ab     = (const float *)d_in[7];
  const float *wq     = (const float *)d_in[8];
  const float *wmem   = (const float *)d_in[9];
  const float *vw     = (const float *)d_in[10];
  const float *convW  = (const float *)d_in[11];
  const float *ldW    = (const float *)d_in[12];
  const float *dWih   = (const float *)d_in[13];
  const float *dWhh   = (const float *)d_in[14];
  const float *db     = (const float *)d_in[15];
  const float *projW  = (const float *)d_in[16];
  const float *projB  = (const float *)d_in[17];
  const float *gateW  = (const float *)d_in[18];
  const float *gateB  = (const float *)d_in[19];

  float *out_mel  = (float *)d_out;
  float *out_gate = out_mel + (size_t)16 * 80 * 200;
  float *out_algn = out_gate + (size_t)16 * 200;

  float *ws = (float *)d_ws;
  u16 *preTu = (u16 *)(ws + OFF_PRETU);
  u16 *pmu   = (u16 *)(ws + OFF_PMU);
  u16 *x1u   = (u16 *)(ws + OFF_Z);   // prenet temp aliased on z (pre-loop only)

  // zero state + barrier area every call
  hipMemsetAsync(ws, 0, STATE_F * sizeof(float), stream);

  uint32_t K1a, K1b, K2a, K2b;
  tf2x32(0u, 42u, 0u, 0u, K1a, K1b);
  tf2x32(0u, 42u, 0u, 1u, K2a, K2b);

  k_prenet1<<<TDEC * BB, 256, 0, stream>>>(dec_in, pw1, x1u, K1a, K1b);
  k_prenet2<<<TDEC * BB, 256, 0, stream>>>(x1u, pw2, preTu, K2a, K2b);
  k_pm<<<64, 256, 0, stream>>>(memory, wmem, pmu);

  k_persist<<<NBLK, 256, 0, stream>>>(ws, memory, mlen,
                                      aWih, aWhh, ab, wq, vw, convW, ldW,
                                      dWih, dWhh, db, projW, projB, gateW, gateB,
                                      out_mel, out_gate, out_algn);
}

// Round 8
// 41938.855 us; speedup vs baseline: 2.4455x; 2.4455x over previous
//
#include <hip/hip_runtime.h>
#include <stdint.h>

typedef unsigned short u16;

#define BB    16
#define TENC  256
#define TDEC  200
#define NMELS 80
#define EDIM  512
#define PREN  256
#define ARN   1024
#define ATTN  128
#define NFILT 32
#define KSIZE 31

// ---- ws layout (floats); total 1,839,104 f = 7.36 MB (proven budget >= 7.44 MB) ----
#define OFF_AW     0          // 4096
#define OFF_AWC    4096       // 4096
#define OFF_AC     8192       // 16384
#define OFF_DC     24576      // 16384
#define OFF_CTX    40960      // 8192  [b][e]
#define OFF_XCAT1  49152      // [pre(256)|ctx(512)|ah(1024)] x16 = 28672
#define OFF_XCAT2  77824      // [ah(1024)|ctx(512)|dh(1024)] x16 = 40960
#define STATE_F    118784
#define OFF_PRETU  118784     // u16[819200]  pre bf16 [t][j*16+b]
#define OFF_PMU    528384     // u16[524288]  pm bf16 [b][j][tt]
#define OFF_Z      790528     // f32[16*65536] split-K partials

__host__ __device__ inline void tf2x32(uint32_t k0, uint32_t k1, uint32_t x0, uint32_t x1,
                                       uint32_t &y0, uint32_t &y1) {
  uint32_t ks2 = k0 ^ k1 ^ 0x1BD11BDAu;
  x0 += k0; x1 += k1;
  const int R0[4] = {13, 15, 26, 6};
  const int R1[4] = {17, 29, 16, 24};
#pragma unroll
  for (int g = 0; g < 5; ++g) {
    const int *R = (g & 1) ? R1 : R0;
#pragma unroll
    for (int i = 0; i < 4; ++i) {
      x0 += x1;
      x1 = (x1 << R[i]) | (x1 >> (32 - R[i]));
      x1 ^= x0;
    }
    switch (g) {
      case 0: x0 += k1;  x1 += ks2 + 1u; break;
      case 1: x0 += ks2; x1 += k0 + 2u;  break;
      case 2: x0 += k0;  x1 += k1 + 3u;  break;
      case 3: x0 += k1;  x1 += ks2 + 4u; break;
      case 4: x0 += ks2; x1 += k0 + 5u;  break;
    }
  }
  y0 = x0; y1 = x1;
}

__device__ inline bool keep_mask(uint32_t k0, uint32_t k1, uint32_t idx) {
  uint32_t y0, y1;
  tf2x32(k0, k1, 0u, idx, y0, y1);
  return (((y0 ^ y1) >> 31) == 0u);
}

__device__ inline float bf2f(u16 v) {
  union { uint32_t u; float f; } x;
  x.u = ((uint32_t)v) << 16;
  return x.f;
}
__device__ inline u16 f2bf(float f) {
  union { float f; uint32_t u; } x;
  x.f = f;
  uint32_t r = ((x.u >> 16) & 1u) + 0x7FFFu;
  return (u16)((x.u + r) >> 16);
}
__device__ inline float sigm(float x) { return 1.f / (1.f + __expf(-x)); }
__device__ inline float ftanh(float x) {
  x = fminf(fmaxf(x, -15.f), 15.f);
  float e = __expf(2.f * x);
  return (e - 1.f) / (e + 1.f);
}

// ---------------- prenet layer 1 ----------------
__global__ __launch_bounds__(256) void k_prenet1(const float *__restrict__ dec_in,
                                                 const float *__restrict__ W1,
                                                 u16 *__restrict__ x1,
                                                 uint32_t k0, uint32_t k1) {
  int bid = blockIdx.x;
  int t = bid >> 4, b = bid & 15;
  int tid = threadIdx.x;
  __shared__ float di[NMELS];
  if (tid < NMELS)
    di[tid] = (t == 0) ? 0.f : dec_in[((size_t)b * NMELS + tid) * TDEC + (t - 1)];
  __syncthreads();
  int j = tid;
  float acc = 0.f;
#pragma unroll 4
  for (int m = 0; m < NMELS; ++m) acc += di[m] * W1[(size_t)m * PREN + j];
  acc = fmaxf(acc, 0.f);
  uint32_t idx = ((uint32_t)(t * BB + b)) * PREN + (uint32_t)j;
  acc = keep_mask(k0, k1, idx) ? acc * 2.f : 0.f;
  x1[(t * BB + b) * PREN + j] = f2bf(acc);
}

// ---------------- prenet layer 2 -> preTu bf16 [t][j*16+b]; t==0 also -> xcat1 f32 ----------------
__global__ __launch_bounds__(256) void k_prenet2(const u16 *__restrict__ x1,
                                                 const float *__restrict__ W2,
                                                 u16 *__restrict__ preTu,
                                                 float *__restrict__ xpre0,
                                                 uint32_t k0, uint32_t k1) {
  int bid = blockIdx.x;
  int t = bid >> 4, b = bid & 15;
  int tid = threadIdx.x;
  __shared__ float xl[PREN];
  xl[tid] = bf2f(x1[(t * BB + b) * PREN + tid]);
  __syncthreads();
  int j = tid;
  float acc = 0.f;
#pragma unroll 4
  for (int k = 0; k < PREN; ++k) acc += xl[k] * W2[(size_t)k * PREN + j];
  acc = fmaxf(acc, 0.f);
  uint32_t idx = ((uint32_t)(t * BB + b)) * PREN + (uint32_t)j;
  acc = keep_mask(k0, k1, idx) ? acc * 2.f : 0.f;
  preTu[(size_t)t * 4096 + j * 16 + b] = f2bf(acc);
  if (t == 0) xpre0[j * 16 + b] = acc;
}

// ---------------- pm = memory @ Wmem, bf16 transposed [b][j][tt] ----------------
__global__ __launch_bounds__(256) void k_pm(const float *__restrict__ memory,
                                            const float *__restrict__ Wmem,
                                            u16 *__restrict__ pmu) {
  int p = blockIdx.x;          // 64 blocks
  int b = p & 15, jt = p >> 4;
  int tt = threadIdx.x;
  float acc[32];
#pragma unroll
  for (int j = 0; j < 32; ++j) acc[j] = 0.f;
  const float *mrow = memory + ((size_t)b * TENC + tt) * EDIM;
  const float *wb = Wmem + jt * 32;
  for (int e = 0; e < EDIM; ++e) {
    float mv = mrow[e];
    const float *wr = wb + (size_t)e * ATTN;
#pragma unroll
    for (int j = 0; j < 32; ++j) acc[j] += mv * wr[j];
  }
#pragma unroll
  for (int j = 0; j < 32; ++j)
    pmu[((size_t)(b * ATTN + jt * 32 + j)) * TENC + tt] = f2bf(acc[j]);
}

// ---------------- split-K GEMM: 2 cols/thread, float2 weight loads ----------------
#define GBODY(w, xr) { float4 x0 = xr[0], x1v = xr[1], x2 = xr[2], x3 = xr[3];            \
  a0[0]+=x0.x*w.x;  a1[0]+=x0.x*w.y;  a0[1]+=x0.y*w.x;  a1[1]+=x0.y*w.y;                  \
  a0[2]+=x0.z*w.x;  a1[2]+=x0.z*w.y;  a0[3]+=x0.w*w.x;  a1[3]+=x0.w*w.y;                  \
  a0[4]+=x1v.x*w.x; a1[4]+=x1v.x*w.y; a0[5]+=x1v.y*w.x; a1[5]+=x1v.y*w.y;                 \
  a0[6]+=x1v.z*w.x; a1[6]+=x1v.z*w.y; a0[7]+=x1v.w*w.x; a1[7]+=x1v.w*w.y;                 \
  a0[8]+=x2.x*w.x;  a1[8]+=x2.x*w.y;  a0[9]+=x2.y*w.x;  a1[9]+=x2.y*w.y;                  \
  a0[10]+=x2.z*w.x; a1[10]+=x2.z*w.y; a0[11]+=x2.w*w.x; a1[11]+=x2.w*w.y;                 \
  a0[12]+=x3.x*w.x; a1[12]+=x3.x*w.y; a0[13]+=x3.y*w.x; a1[13]+=x3.y*w.y;                 \
  a0[14]+=x3.z*w.x; a1[14]+=x3.z*w.y; a0[15]+=x3.w*w.x; a1[15]+=x3.w*w.y; }

template <int BK>
__global__ __launch_bounds__(128) void k_zgemm(const float *__restrict__ Wih,
                                               const float *__restrict__ Whh,
                                               int lenIH,
                                               const float *__restrict__ xcat,
                                               float *__restrict__ z) {
  __shared__ float xs[BK * 16];
  int tid = threadIdx.x;
  int col = blockIdx.x * 256 + tid * 2;
  int kbase = blockIdx.y * BK;
  const float4 *xsrc = (const float4 *)(xcat + (size_t)kbase * 16);
#pragma unroll
  for (int i = 0; i < BK / 32; ++i) ((float4 *)xs)[tid + i * 128] = xsrc[tid + i * 128];
  __syncthreads();
  float a0[16], a1[16];
#pragma unroll
  for (int b = 0; b < 16; ++b) { a0[b] = 0.f; a1[b] = 0.f; }
  int n1 = lenIH - kbase;
  n1 = n1 < 0 ? 0 : (n1 > BK ? BK : n1);
  if (n1 == BK) {
    const float *wp = Wih + (size_t)kbase * 4096 + col;
#pragma unroll 4
    for (int kk = 0; kk < BK; ++kk) {
      float2 w = *(const float2 *)(wp + (size_t)kk * 4096);
      const float4 *xr = (const float4 *)(xs + kk * 16);
      GBODY(w, xr)
    }
  } else if (n1 == 0) {
    const float *wp = Whh + (size_t)(kbase - lenIH) * 4096 + col;
#pragma unroll 4
    for (int kk = 0; kk < BK; ++kk) {
      float2 w = *(const float2 *)(wp + (size_t)kk * 4096);
      const float4 *xr = (const float4 *)(xs + kk * 16);
      GBODY(w, xr)
    }
  } else {
    const float *wp = Wih + (size_t)kbase * 4096 + col;
    for (int kk = 0; kk < n1; ++kk) {
      float2 w = *(const float2 *)(wp + (size_t)kk * 4096);
      const float4 *xr = (const float4 *)(xs + kk * 16);
      GBODY(w, xr)
    }
    const float *wp2 = Whh + col;   // rows start at kbase+n1-lenIH == 0
    for (int kk = n1; kk < BK; ++kk) {
      float2 w = *(const float2 *)(wp2 + (size_t)(kk - n1) * 4096);
      const float4 *xr = (const float4 *)(xs + kk * 16);
      GBODY(w, xr)
    }
  }
  float *zo = z + ((size_t)blockIdx.y * 16) * 4096 + col;
#pragma unroll
  for (int b = 0; b < 16; ++b) {
    float2 v; v.x = a0[b]; v.y = a1[b];
    *(float2 *)(zo + (size_t)b * 4096) = v;
  }
}

// ---------------- fused aLSTM-act + attention (16 blocks x 1024 thr) ----------------
__global__ __launch_bounds__(1024) void k_att(const float *__restrict__ z1p, int nch,
                                              const float *__restrict__ ab,
                                              float *__restrict__ ac,
                                              float *__restrict__ ahT1, float *__restrict__ ahT2,
                                              float *__restrict__ aw, float *__restrict__ awc,
                                              const u16 *__restrict__ pmu,
                                              const float *__restrict__ Wq,
                                              const float *__restrict__ vw,
                                              const float *__restrict__ convW,
                                              const float *__restrict__ ldW,
                                              const float *__restrict__ memory,
                                              const int *__restrict__ mlen,
                                              float *__restrict__ ctx,
                                              float *__restrict__ ctxT1, float *__restrict__ ctxT2,
                                              float *__restrict__ align_out, int t) {
  int b = blockIdx.x;
  int tid = threadIdx.x;
  __shared__ float ah_l[ARN];
  __shared__ float aw_l[288], awc_l[288];
  __shared__ float lc[TENC * 33];
  __shared__ float pqp[1024];
  __shared__ float pq[ATTN];
  __shared__ float ep[TENC * 4];
  __shared__ float e_l[TENC];
  __shared__ float cp[2][EDIM];
  __shared__ float red[32];
  __shared__ float s_max, s_inv;

  // phase A: reduce z1 partials -> ah
  {
    int u = tid;
    float zi = 0.f, zf = 0.f, zg = 0.f, zo = 0.f;
    for (int kc = 0; kc < nch; ++kc) {
      const float *zb = z1p + ((size_t)(kc * 16 + b)) * 4096;
      zi += zb[u]; zf += zb[u + 1024]; zg += zb[u + 2048]; zo += zb[u + 3072];
    }
    zi += ab[u]; zf += ab[u + 1024]; zg += ab[u + 2048]; zo += ab[u + 3072];
    float cn = sigm(zf) * ac[b * 1024 + u] + sigm(zi) * ftanh(zg);
    float hn = sigm(zo) * ftanh(cn);
    ac[b * 1024 + u] = cn;
    ahT1[u * 16 + b] = hn;
    ahT2[u * 16 + b] = hn;
    ah_l[u] = hn;
  }
  if (tid < TENC) { aw_l[16 + tid] = aw[b * 256 + tid]; awc_l[16 + tid] = awc[b * 256 + tid]; }
  if (tid < 16) {
    aw_l[tid] = 0.f; aw_l[272 + tid] = 0.f;
    awc_l[tid] = 0.f; awc_l[272 + tid] = 0.f;
  }
  __syncthreads();

  // pq partials
  {
    int j = tid & 127, kc = tid >> 7;
    float a = 0.f;
    const float *wq = Wq + (size_t)(kc * 128) * ATTN + j;
#pragma unroll 4
    for (int kk = 0; kk < 128; ++kk) a += ah_l[kc * 128 + kk] * wq[(size_t)kk * ATTN];
    pqp[j * 8 + kc] = a;
  }
  // conv
  {
    int tt = tid & 255, fg = tid >> 8;
    float acc8[8] = {0, 0, 0, 0, 0, 0, 0, 0};
    for (int k = 0; k < KSIZE; ++k) {
      float a = aw_l[tt + k + 1];
      float c = awc_l[tt + k + 1];
#pragma unroll
      for (int f8 = 0; f8 < 8; ++f8) {
        int f = fg * 8 + f8;
        acc8[f8] += a * convW[f * 62 + k] + c * convW[f * 62 + 31 + k];
      }
    }
#pragma unroll
    for (int f8 = 0; f8 < 8; ++f8) lc[tt * 33 + fg * 8 + f8] = acc8[f8];
  }
  __syncthreads();
  if (tid < ATTN) {
    float s = 0.f;
#pragma unroll
    for (int kc = 0; kc < 8; ++kc) s += pqp[tid * 8 + kc];
    pq[tid] = s;
  }
  __syncthreads();
  // energies: 4 groups x 32 j, register acc, uniform ldW (s_load)
  {
    int tt = tid & 255, g = tid >> 8;
    float acc[32];
#pragma unroll
    for (int j = 0; j < 32; ++j) acc[j] = 0.f;
    for (int f = 0; f < NFILT; ++f) {
      float lv = lc[tt * 33 + f];
      const float *lw = ldW + f * ATTN + g * 32;
#pragma unroll
      for (int j = 0; j < 32; ++j) acc[j] += lv * lw[j];
    }
    const u16 *pmrow = pmu + ((size_t)(b * ATTN + g * 32)) * TENC + tt;
    const float *vwh = vw + g * 32;
    const float *pqh = pq + g * 32;
    float esum = 0.f;
#pragma unroll 4
    for (int j = 0; j < 32; ++j) {
      float s = acc[j] + pqh[j] + bf2f(pmrow[(size_t)j * TENC]);
      esum += ftanh(s) * vwh[j];
    }
    ep[tt * 4 + g] = esum;
  }
  __syncthreads();
  int len = mlen[b];
  if (tid < TENC) {
    float e = ep[tid * 4] + ep[tid * 4 + 1] + ep[tid * 4 + 2] + ep[tid * 4 + 3];
    if (tid >= len) e = -1e9f;
    e_l[tid] = e;
  }
  __syncthreads();
  if (tid < 32) {
    float m = -1e30f;
#pragma unroll
    for (int i = 0; i < 8; ++i) m = fmaxf(m, e_l[tid * 8 + i]);
    red[tid] = m;
  }
  __syncthreads();
  if (tid == 0) {
    float m = -1e30f;
    for (int i = 0; i < 32; ++i) m = fmaxf(m, red[i]);
    s_max = m;
  }
  __syncthreads();
  if (tid < TENC) e_l[tid] = __expf(e_l[tid] - s_max);
  __syncthreads();
  if (tid < 32) {
    float s = 0.f;
#pragma unroll
    for (int i = 0; i < 8; ++i) s += e_l[tid * 8 + i];
    red[tid] = s;
  }
  __syncthreads();
  if (tid == 0) {
    float s = 0.f;
    for (int i = 0; i < 32; ++i) s += red[i];
    s_inv = 1.f / s;
  }
  __syncthreads();
  if (tid < TENC) {
    float w = e_l[tid] * s_inv;
    e_l[tid] = w;
    aw[b * 256 + tid] = w;
    awc[b * 256 + tid] = awc_l[16 + tid] + w;
    align_out[((size_t)b * TDEC + t) * TENC + tid] = w;
  }
  __syncthreads();
  // ctx = w @ memory
  {
    int e = tid & 511, h = tid >> 9;
    int t0 = h * 128, t1 = min(len, (h + 1) * 128);
    float a = 0.f;
    for (int tt = t0; tt < t1; ++tt)
      a += e_l[tt] * memory[((size_t)b * TENC + tt) * EDIM + e];
    cp[h][e] = a;
  }
  __syncthreads();
  if (tid < EDIM) {
    float v = cp[0][tid] + cp[1][tid];
    ctx[b * EDIM + tid] = v;
    ctxT1[tid * 16 + b] = v;
    ctxT2[tid * 16 + b] = v;
  }
}

// ---------------- fused dLSTM-act + projection (24 blocks x 512 thr) ----------------
__global__ __launch_bounds__(512) void k_out(const float *__restrict__ z2p, int nch,
                                             const float *__restrict__ db,
                                             float *__restrict__ dc,
                                             float *__restrict__ dhT,
                                             const float *__restrict__ ctx,
                                             const float *__restrict__ projW,
                                             const float *__restrict__ projB,
                                             const float *__restrict__ gateW,
                                             const float *__restrict__ gateB,
                                             const u16 *__restrict__ preTu,
                                             float *__restrict__ xpre,
                                             float *__restrict__ mel_out,
                                             float *__restrict__ gate_out, int t) {
  int p = blockIdx.x;
  int tid = threadIdx.x;
  if (p >= 16) {
    if (t + 1 < TDEC) {
      int idx = (p - 16) * 512 + tid;
      xpre[idx] = bf2f(preTu[(size_t)(t + 1) * 4096 + idx]);
    }
    return;
  }
  int b = p;
  __shared__ float xl[1536];
  __shared__ float part[6 * 81];
#pragma unroll
  for (int r = 0; r < 2; ++r) {
    int u = r * 512 + tid;
    float zi = 0.f, zf = 0.f, zg = 0.f, zo = 0.f;
    for (int kc = 0; kc < nch; ++kc) {
      const float *zb = z2p + ((size_t)(kc * 16 + b)) * 4096;
      zi += zb[u]; zf += zb[u + 1024]; zg += zb[u + 2048]; zo += zb[u + 3072];
    }
    zi += db[u]; zf += db[u + 1024]; zg += db[u + 2048]; zo += db[u + 3072];
    float cn = sigm(zf) * dc[b * 1024 + u] + sigm(zi) * ftanh(zg);
    float hn = sigm(zo) * ftanh(cn);
    dc[b * 1024 + u] = cn;
    dhT[u * 16 + b] = hn;
    xl[u] = hn;
  }
  xl[1024 + tid] = ctx[b * 512 + tid];
  __syncthreads();
  // projection: 6 k-groups x (80 cols + gate)
  {
    int col, kc;
    float a = 0.f;
    if (tid < 480) {
      col = tid % 80; kc = tid / 80;
      const float *wp = projW + (size_t)(kc * 256) * 80 + col;
      const float *xk = xl + kc * 256;
#pragma unroll 4
      for (int kk = 0; kk < 256; ++kk) a += xk[kk] * wp[(size_t)kk * 80];
      part[kc * 81 + col] = a;
    } else if (tid < 486) {
      kc = tid - 480;
      const float *xk = xl + kc * 256;
      const float *gk = gateW + kc * 256;
#pragma unroll 4
      for (int kk = 0; kk < 256; ++kk) a += xk[kk] * gk[kk];
      part[kc * 81 + 80] = a;
    }
  }
  __syncthreads();
  if (tid < 81) {
    float s = 0.f;
#pragma unroll
    for (int kc = 0; kc < 6; ++kc) s += part[kc * 81 + tid];
    if (tid < 80) {
      s += projB[tid];
      mel_out[((size_t)b * 80 + tid) * TDEC + t] = s;
    } else {
      s += gateB[0];
      gate_out[(size_t)b * TDEC + t] = s;
    }
  }
}

extern "C" void kernel_launch(void *const *d_in, const int *in_sizes, int n_in,
                              void *d_out, int out_size, void *d_ws, size_t ws_size,
                              hipStream_t stream) {
  (void)in_sizes; (void)n_in; (void)out_size; (void)ws_size;
  const float *memory = (const float *)d_in[0];
  const float *dec_in = (const float *)d_in[1];
  const int   *mlen   = (const int *)d_in[2];
  const float *pw1    = (const float *)d_in[3];
  const float *pw2    = (const float *)d_in[4];
  const float *aWih   = (const float *)d_in[5];
  const float *aWhh   = (const float *)d_in[6];
  const float *ab     = (const float *)d_in[7];
  const float *wq     = (const float *)d_in[8];
  const float *wmem   = (const float *)d_in[9];
  const float *vw     = (const float *)d_in[10];
  const float *convW  = (const float *)d_in[11];
  const float *ldW    = (const float *)d_in[12];
  const float *dWih   = (const float *)d_in[13];
  const float *dWhh   = (const float *)d_in[14];
  const float *db     = (const float *)d_in[15];
  const float *projW  = (const float *)d_in[16];
  const float *projB  = (const float *)d_in[17];
  const float *gateW  = (const float *)d_in[18];
  const float *gateB  = (const float *)d_in[19];

  float *out_mel  = (float *)d_out;
  float *out_gate = out_mel + (size_t)16 * 80 * 200;
  float *out_algn = out_gate + (size_t)16 * 200;

  float *ws = (float *)d_ws;
  float *aw    = ws + OFF_AW;
  float *awc   = ws + OFF_AWC;
  float *ac    = ws + OFF_AC;
  float *dc    = ws + OFF_DC;
  float *ctx   = ws + OFF_CTX;
  float *xcat1 = ws + OFF_XCAT1;           // [pre | ctxT1 | ahT1]
  float *xcat2 = ws + OFF_XCAT2;           // [ahT2 | ctxT2 | dhT]
  float *xpre  = xcat1;
  float *ctxT1 = xcat1 + 4096;
  float *ahT1  = xcat1 + 12288;
  float *ahT2  = xcat2;
  float *ctxT2 = xcat2 + 16384;
  float *dhT   = xcat2 + 24576;
  u16 *preTu = (u16 *)(ws + OFF_PRETU);
  u16 *pmu   = (u16 *)(ws + OFF_PMU);
  float *z   = ws + OFF_Z;
  u16 *x1u   = (u16 *)z;                   // prenet temp alias (pre-loop only)

  hipMemsetAsync(ws, 0, STATE_F * sizeof(float), stream);

  uint32_t K1a, K1b, K2a, K2b;
  tf2x32(0u, 42u, 0u, 0u, K1a, K1b);
  tf2x32(0u, 42u, 0u, 1u, K2a, K2b);

  k_prenet1<<<TDEC * BB, 256, 0, stream>>>(dec_in, pw1, x1u, K1a, K1b);
  k_prenet2<<<TDEC * BB, 256, 0, stream>>>(x1u, pw2, preTu, xpre, K2a, K2b);
  k_pm<<<64, 256, 0, stream>>>(memory, wmem, pmu);

  for (int t = 0; t < TDEC; ++t) {
    // z1 = [pre|ctx|ah] @ [aWih;aWhh]   K=1792, BK=128 -> 14 chunks x 16 colblocks
    k_zgemm<128><<<dim3(16, 14), 128, 0, stream>>>(aWih, aWhh, 768, xcat1, z);
    k_att<<<16, 1024, 0, stream>>>(z, 14, ab, ac, ahT1, ahT2, aw, awc, pmu,
                                   wq, vw, convW, ldW, memory, mlen,
                                   ctx, ctxT1, ctxT2, out_algn, t);
    // z2 = [ah|ctx|dh] @ [dWih;dWhh]   K=2560, BK=160 -> 16 chunks x 16 colblocks
    k_zgemm<160><<<dim3(16, 16), 128, 0, stream>>>(dWih, dWhh, 1536, xcat2, z);
    k_out<<<24, 512, 0, stream>>>(z, 16, db, dc, dhT, ctx, projW, projB,
                                  gateW, gateB, preTu, xpre,
                                  out_mel, out_gate, t);
  }
}